// Round 6
// baseline (139.888 us; speedup 1.0000x reference)
//
#include <hip/hip_runtime.h>
#include <math.h>

#define TAU_F 0.02f
#define NB 64
#define NQ 32
#define NS 256
#define ND 128
#define MAXT 12          // max 32-row tiles per doc (sum ceil(c_m/32) <= 12)
#define PERMSTRIDE 384   // MAXT*32

typedef __bf16 bf16x8 __attribute__((ext_vector_type(8)));
typedef float f32x16 __attribute__((ext_vector_type(16)));

// workspace layout (bytes): only simout now
#define OFF_SIMOUT  0u          // 64*64*5*4 = 81920

// ---------------------------------------------------------------------------
// Kernel 1 (fully fused): one block per (c, b-pair), XCD-swizzled.
// Phase 1: block re-derives doc c's modality partition (ballot ranking, pad
//   segments to x32 by duplicating the first token of the segment — position
//   is the max-invariant duplicate).
// Phase 2: q fragments (2 b's) loaded fp32->bf16 straight into 64 VGPRs,
//   B-operand layout B[k=(lane>>5)*8+j][n=lane&31], k-chunk kc: k=kc*16+...
// Phase 3: per 32-row doc tile: gather rows via sperm, cvt fp32->bf16 into
//   A-operand frags, 8 MFMA (32x32x16) per b, max-epilogue into vmax[m].
// C/D layout (m74/m101, HW-verified R5): col=lane&31, row-fold = 15 v_max
//   over regs + shfl_xor(32).
// ---------------------------------------------------------------------------
__global__ __launch_bounds__(256) void
fused_kernel(const float* __restrict__ qemb, const float* __restrict__ demb,
             const int* __restrict__ mod, const int* __restrict__ qmask,
             float* __restrict__ simout) {
    int blk = blockIdx.x;
    // XCD swizzle: xcd = blk&7 gets docs [xcd*8, xcd*8+8)
    int c  = (blk & 7) * 8 + (blk >> 8);
    int bp = (blk >> 3) & 31;
    int b0 = bp * 2;
    int tid = threadIdx.x;
    int lane = tid & 63, wv = tid >> 6;
    int li32 = lane & 31, kh = lane >> 5;

    // ---- Phase 2 first: issue query loads early (independent of partition)
    bf16x8 bfrag[2][8];
#pragma unroll
    for (int bi = 0; bi < 2; ++bi) {
        const float* qb = qemb + ((size_t)(b0 + bi) * NQ + li32) * ND + kh * 8;
#pragma unroll
        for (int kc = 0; kc < 8; ++kc) {
            float4 a = *(const float4*)(qb + kc * 16);
            float4 b2 = *(const float4*)(qb + kc * 16 + 4);
            bf16x8 o;
            o[0] = (__bf16)a.x;  o[1] = (__bf16)a.y;  o[2] = (__bf16)a.z;  o[3] = (__bf16)a.w;
            o[4] = (__bf16)b2.x; o[5] = (__bf16)b2.y; o[6] = (__bf16)b2.z; o[7] = (__bf16)b2.w;
            bfrag[bi][kc] = o;
        }
    }

    // ---- Phase 1: partition ----
    __shared__ int sperm[PERMSTRIDE];
    __shared__ int stilemod[MAXT];
    __shared__ int wcnt[4][4];      // [wave][modality-1]
    __shared__ int firsts[4];
    __shared__ int sT;

    if (tid < 4) firsts[tid] = NS;
    __syncthreads();
    int m_tok = mod[c * NS + tid];
    unsigned long long mk1 = __ballot(m_tok == 1);
    unsigned long long mk2 = __ballot(m_tok == 2);
    unsigned long long mk3 = __ballot(m_tok == 3);
    unsigned long long mk4 = __ballot(m_tok == 4);
    if (lane == 0) {
        wcnt[wv][0] = __popcll(mk1); wcnt[wv][1] = __popcll(mk2);
        wcnt[wv][2] = __popcll(mk3); wcnt[wv][3] = __popcll(mk4);
    }
    if (m_tok) atomicMin(&firsts[m_tok - 1], tid);
    __syncthreads();

    int cnt1 = wcnt[0][0] + wcnt[1][0] + wcnt[2][0] + wcnt[3][0];
    int cnt2 = wcnt[0][1] + wcnt[1][1] + wcnt[2][1] + wcnt[3][1];
    int cnt3 = wcnt[0][2] + wcnt[1][2] + wcnt[2][2] + wcnt[3][2];
    int cnt4 = wcnt[0][3] + wcnt[1][3] + wcnt[2][3] + wcnt[3][3];
    int pad1 = (cnt1 + 31) & ~31, pad2 = (cnt2 + 31) & ~31;
    int pad3 = (cnt3 + 31) & ~31, pad4 = (cnt4 + 31) & ~31;
    int off1 = 0, off2 = pad1, off3 = pad2 + off2, off4 = pad3 + off3;
    int total = off4 + pad4;
    if (tid == 0) sT = total >> 5;

    if (m_tok) {
        unsigned long long mk = (m_tok == 1) ? mk1 : (m_tok == 2) ? mk2
                              : (m_tok == 3) ? mk3 : mk4;
        int off = (m_tok == 1) ? off1 : (m_tok == 2) ? off2
                : (m_tok == 3) ? off3 : off4;
        int rank = __popcll(mk & ((1ull << lane) - 1ull));
        for (int w = 0; w < 4; ++w)
            if (w < wv) rank += wcnt[w][m_tok - 1];
        sperm[off + rank] = tid;
    }
    // pad slots: duplicate the segment's first token (max-invariant)
    if (tid < 128) {
        int m = tid >> 5, p = tid & 31;
        int cm = (m == 0) ? cnt1 : (m == 1) ? cnt2 : (m == 2) ? cnt3 : cnt4;
        int pm = (m == 0) ? pad1 : (m == 1) ? pad2 : (m == 2) ? pad3 : pad4;
        int om = (m == 0) ? off1 : (m == 1) ? off2 : (m == 2) ? off3 : off4;
        int slot = cm + p;
        if (slot < pm) sperm[om + slot] = firsts[m];
    }
    if (tid < MAXT) {
        int t0 = tid * 32;
        int m = 4;
        if (t0 < off2) m = 1; else if (t0 < off3) m = 2; else if (t0 < off4) m = 3;
        stilemod[tid] = m;
    }
    __syncthreads();

    // ---- Phase 3: tile loop ----
    float vmax[2][4];
#pragma unroll
    for (int bi = 0; bi < 2; ++bi)
#pragma unroll
        for (int m = 0; m < 4; ++m) vmax[bi][m] = -1e30f;

    int T = sT;
    const float* dbase = demb + (size_t)c * NS * ND + kh * 8;
    for (int t = wv; t < T; t += 4) {
        int r32 = sperm[t * 32 + li32];
        const float* rowp = dbase + (size_t)r32 * ND;
        bf16x8 af[8];
#pragma unroll
        for (int kc = 0; kc < 8; ++kc) {
            float4 a = *(const float4*)(rowp + kc * 16);
            float4 b2 = *(const float4*)(rowp + kc * 16 + 4);
            bf16x8 o;
            o[0] = (__bf16)a.x;  o[1] = (__bf16)a.y;  o[2] = (__bf16)a.z;  o[3] = (__bf16)a.w;
            o[4] = (__bf16)b2.x; o[5] = (__bf16)b2.y; o[6] = (__bf16)b2.z; o[7] = (__bf16)b2.w;
            af[kc] = o;
        }
        int tm = stilemod[t];   // wave-uniform
#pragma unroll
        for (int bi = 0; bi < 2; ++bi) {
            f32x16 acc = {0.f,0.f,0.f,0.f,0.f,0.f,0.f,0.f,0.f,0.f,0.f,0.f,0.f,0.f,0.f,0.f};
#pragma unroll
            for (int kc = 0; kc < 8; ++kc)
                acc = __builtin_amdgcn_mfma_f32_32x32x16_bf16(af[kc], bfrag[bi][kc], acc, 0, 0, 0);
            float v = acc[0];
#pragma unroll
            for (int r = 1; r < 16; ++r) v = fmaxf(v, acc[r]);
            v = fmaxf(v, __shfl_xor(v, 32, 64));   // combine row halves
            switch (tm) {
            case 1:  vmax[bi][0] = fmaxf(vmax[bi][0], v); break;
            case 2:  vmax[bi][1] = fmaxf(vmax[bi][1], v); break;
            case 3:  vmax[bi][2] = fmaxf(vmax[bi][2], v); break;
            default: vmax[bi][3] = fmaxf(vmax[bi][3], v); break;
            }
        }
    }

    // cross-wave reduce: lv[wave][bi][m][q]
    __shared__ float lv[4][2][4][32];   // 4 KB
    if (lane < 32) {
#pragma unroll
        for (int bi = 0; bi < 2; ++bi)
#pragma unroll
            for (int m = 0; m < 4; ++m) lv[wv][bi][m][lane] = vmax[bi][m];
    }
    __syncthreads();
    __shared__ float l2s[2][4][32];     // 1 KB
    {
        int bi = tid >> 7, m = (tid >> 5) & 3, q = tid & 31;
        float v = fmaxf(fmaxf(lv[0][bi][m][q], lv[1][bi][m][q]),
                        fmaxf(lv[2][bi][m][q], lv[3][bi][m][q]));
        l2s[bi][m][q] = v;
    }
    __syncthreads();
    if (tid < 64) {
        int bi = tid >> 5, q = tid & 31;
        float m1 = l2s[bi][0][q], m2 = l2s[bi][1][q];
        float m3 = l2s[bi][2][q], m4 = l2s[bi][3][q];
        int b = b0 + bi;
        float agg = fmaxf(fmaxf(m1, m2), fmaxf(m3, m4));
        float s0 = (qmask[b * NQ + q] != 0) ? agg : 0.f;
        float s1 = m1, s2 = m2, s3 = m3, s4 = m4;
#pragma unroll
        for (int off = 16; off >= 1; off >>= 1) {   // stays within 32-lane half
            s0 += __shfl_xor(s0, off, 64);
            s1 += __shfl_xor(s1, off, 64);
            s2 += __shfl_xor(s2, off, 64);
            s3 += __shfl_xor(s3, off, 64);
            s4 += __shfl_xor(s4, off, 64);
        }
        if (q == 0) {
            float* o = simout + ((size_t)b * NB + c) * 5;   // UNNORMALIZED sums
            o[0] = s0; o[1] = s1; o[2] = s2; o[3] = s3; o[4] = s4;
        }
    }
}

// ---------------------------------------------------------------------------
// Kernel 2: per-row two-pass logsumexp over 319 logits, mean over rows.
// Row b multiset: {sim[b,c]: c!=b} U {sims[b,c,m]: all c, m=1..4};
// positive = sims[b,b,query_types[b]]. Computes qnorm from qmask here.
// ---------------------------------------------------------------------------
__global__ void loss_kernel(const float* __restrict__ simout, const int* __restrict__ qtypes,
                            const int* __restrict__ qmask, float* __restrict__ out) {
    __shared__ float lloss[NB];
    int tid = threadIdx.x;
    int r = tid >> 2, i = tid & 3;
    int cnt = 0;
#pragma unroll
    for (int j = 0; j < 8; ++j) cnt += (qmask[r * NQ + i * 8 + j] != 0);
    cnt += __shfl_xor(cnt, 1, 64);
    cnt += __shfl_xor(cnt, 2, 64);
    float scale = 1.0f / (TAU_F * (float)(cnt > 0 ? cnt : 1));

    float mx = -1e30f;
    for (int cc = 0; cc < 16; ++cc) {
        int c = i * 16 + cc;
        const float* p = simout + ((size_t)r * NB + c) * 5;
#pragma unroll
        for (int j = 0; j < 5; ++j) {
            if (j == 0 && c == r) continue;
            mx = fmaxf(mx, p[j] * scale);
        }
    }
    mx = fmaxf(mx, __shfl_xor(mx, 1, 64));
    mx = fmaxf(mx, __shfl_xor(mx, 2, 64));
    float sum = 0.f;
    for (int cc = 0; cc < 16; ++cc) {
        int c = i * 16 + cc;
        const float* p = simout + ((size_t)r * NB + c) * 5;
#pragma unroll
        for (int j = 0; j < 5; ++j) {
            if (j == 0 && c == r) continue;
            sum += expf(p[j] * scale - mx);
        }
    }
    sum += __shfl_xor(sum, 1, 64);
    sum += __shfl_xor(sum, 2, 64);
    if (i == 0) {
        float pos = simout[((size_t)r * NB + r) * 5 + qtypes[r]] * scale;
        lloss[r] = logf(sum) + mx - pos;
    }
    __syncthreads();
    if (tid == 0) {
        float s = 0.f;
        for (int r2 = 0; r2 < NB; ++r2) s += lloss[r2];
        out[0] = s * (1.0f / NB);
    }
}

// ---------------------------------------------------------------------------
extern "C" void kernel_launch(void* const* d_in, const int* in_sizes, int n_in,
                              void* d_out, int out_size, void* d_ws, size_t ws_size,
                              hipStream_t stream) {
    const float* qemb   = (const float*)d_in[0];
    const float* demb   = (const float*)d_in[1];
    const int*   mod    = (const int*)d_in[2];
    const int*   qtypes = (const int*)d_in[3];
    const int*   qmask  = (const int*)d_in[4];

    char* ws = (char*)d_ws;
    float* simout = (float*)(ws + OFF_SIMOUT);

    fused_kernel<<<2048, 256, 0, stream>>>(qemb, demb, mod, qmask, simout);
    loss_kernel<<<1, 256, 0, stream>>>(simout, qtypes, qmask, (float*)d_out);
}

// Round 7
// 94.910 us; speedup vs baseline: 1.4739x; 1.4739x over previous
//
#include <hip/hip_runtime.h>
#include <math.h>

#define TAU_F 0.02f
#define NB 64
#define NQ 32
#define NS 256
#define ND 128
#define MAXT 12          // max 32-row tiles per doc (sum ceil(c_m/32) <= 11)
#define PERMSTRIDE 384   // MAXT*32

typedef __bf16 bf16x8 __attribute__((ext_vector_type(8)));
typedef float f32x16 __attribute__((ext_vector_type(16)));

// workspace layout (bytes)
#define OFF_TILEMOD 0u          // 64*12*4 = 3072
#define OFF_TCOUNT  4096u       // 64*4
#define OFF_DFRAG   16384u      // 64*12*8*64*16 = 6291456
#define OFF_QFRAG   6307840u    // 64*8*64*16    = 524288
#define OFF_SIMOUT  6832128u    // 64*64*5*4     = 81920
#define OFF_RED     6914048u    // counter @ +0, acc @ +64

// ---------------------------------------------------------------------------
// Kernel 1 (fused prep + fragment swizzle), pad-to-32 for 32x32x16 MFMA.
// Blocks 0..63: doc c — modality partition (stable, pad segments to x32 by
//   duplicating the segment's first token; max-invariant), then fp32->bf16
//   swizzle into MFMA A-operand layout. Block 0 zeroes the loss reduction.
// Blocks 64..127: query b — B-operand layout.
// ---------------------------------------------------------------------------
__global__ __launch_bounds__(256) void
prep_frag_kernel(const float* __restrict__ qemb, const float* __restrict__ demb,
                 const int* __restrict__ mod,
                 __bf16* __restrict__ qfrag, __bf16* __restrict__ dfrag,
                 int* __restrict__ tilemod_g, int* __restrict__ tcount_g,
                 int* __restrict__ red) {
    int blk = blockIdx.x;
    int tid = threadIdx.x;
    int lane = tid & 63, wv = tid >> 6;
    int li32 = lane & 31, kh = lane >> 5;

    if (blk == 0 && tid == 0) { red[0] = 0; ((float*)red)[16] = 0.f; }

    if (blk >= NB) {
        // ---- query fragments: lane holds q col li32, k = kc*16 + kh*8 + j ----
        int b = blk - NB;
#pragma unroll
        for (int i = 0; i < 2; ++i) {
            int kc = wv * 2 + i;               // 0..7
            int k0 = kc * 16 + kh * 8;
            const float* src = qemb + ((size_t)b * NQ + li32) * ND + k0;
            float4 a = *(const float4*)src;
            float4 bq = *(const float4*)(src + 4);
            bf16x8 o;
            o[0] = (__bf16)a.x;  o[1] = (__bf16)a.y;  o[2] = (__bf16)a.z;  o[3] = (__bf16)a.w;
            o[4] = (__bf16)bq.x; o[5] = (__bf16)bq.y; o[6] = (__bf16)bq.z; o[7] = (__bf16)bq.w;
            *(bf16x8*)(qfrag + (((size_t)b * 8 + kc) * 64 + lane) * 8) = o;
        }
        return;
    }

    // ---- doc partition + fragments ----
    int c = blk;
    __shared__ int smod[NS];
    __shared__ int sperm[PERMSTRIDE];
    __shared__ int counts[5], firsts[5], offs[5], padded[5];
    __shared__ int stilemod[MAXT];
    __shared__ int sT;

    if (tid < 5) { counts[tid] = 0; firsts[tid] = NS; }
    __syncthreads();
    int m_tok = mod[c * NS + tid];
    smod[tid] = m_tok;
    if (m_tok) { atomicAdd(&counts[m_tok], 1); atomicMin(&firsts[m_tok], tid); }
    __syncthreads();
    if (tid == 0) {
        int pos = 0;
        for (int m = 1; m <= 4; ++m) {
            offs[m] = pos;
            int p = (counts[m] + 31) & ~31;
            padded[m] = p;
            for (int t = pos >> 5; t < (pos + p) >> 5; ++t) stilemod[t] = m;
            pos += p;
        }
        sT = pos >> 5;
        tcount_g[c] = pos >> 5;
    }
    __syncthreads();
    // stable rank within modality, scatter into sperm
    if (m_tok) {
        int rank = 0;
        for (int s = 0; s < tid; ++s) rank += (smod[s] == m_tok);
        sperm[offs[m_tok] + rank] = tid;
    }
    // pad slots get the segment's first token (max-invariant duplicate)
    if (tid < 4) {
        int m = tid + 1;
        for (int p = counts[m]; p < padded[m]; ++p) sperm[offs[m] + p] = firsts[m];
    }
    __syncthreads();
    int T = sT;
    if (tid < T) tilemod_g[c * MAXT + tid] = stilemod[tid];

    // fragment swizzle: lane holds doc row li32 of tile t, k = kc*16+kh*8+j
    for (int kc = wv; kc < 8; kc += 4) {
        int k0 = kc * 16 + kh * 8;
        for (int t = 0; t < T; ++t) {
            int srow = sperm[t * 32 + li32];
            const float* src = demb + ((size_t)c * NS + srow) * ND + k0;
            float4 a = *(const float4*)src;
            float4 bq = *(const float4*)(src + 4);
            bf16x8 o;
            o[0] = (__bf16)a.x;  o[1] = (__bf16)a.y;  o[2] = (__bf16)a.z;  o[3] = (__bf16)a.w;
            o[4] = (__bf16)bq.x; o[5] = (__bf16)bq.y; o[6] = (__bf16)bq.z; o[7] = (__bf16)bq.w;
            *(bf16x8*)(dfrag + (((size_t)(c * MAXT + t) * 8 + kc) * 64 + lane) * 8) = o;
        }
    }
}

// ---------------------------------------------------------------------------
// Kernel 2: main, 32x32x16 MFMA (unchanged from R5 — absmax 0.0 verified).
// One block per (c, 2 b's); XCD-swizzled. B-operands in 64 VGPRs, no LDS in
// the K-loop. C/D layout (m74/m101): col=lane&31, fold = 15 v_max + shfl(32).
// ---------------------------------------------------------------------------
__global__ __launch_bounds__(256) void
main_kernel(const __bf16* __restrict__ dfrag, const __bf16* __restrict__ qfrag,
            const int* __restrict__ tilemod, const int* __restrict__ tcount,
            const int* __restrict__ qmask, float* __restrict__ simout) {
    int blk = blockIdx.x;
    int c  = (blk & 7) * 8 + (blk >> 8);
    int bp = (blk >> 3) & 31;
    int b0 = bp * 2;
    int tid = threadIdx.x;
    int lane = tid & 63, wv = tid >> 6;

    bf16x8 bfrag[2][8];
#pragma unroll
    for (int bi = 0; bi < 2; ++bi)
#pragma unroll
        for (int kc = 0; kc < 8; ++kc)
            bfrag[bi][kc] = *(const bf16x8*)(qfrag + (((size_t)(b0 + bi) * 8 + kc) * 64 + lane) * 8);

    float vmax[2][4];
#pragma unroll
    for (int bi = 0; bi < 2; ++bi)
#pragma unroll
        for (int m = 0; m < 4; ++m) vmax[bi][m] = -1e30f;

    int T = tcount[c];
    for (int t = wv; t < T; t += 4) {
        bf16x8 af[8];
#pragma unroll
        for (int kc = 0; kc < 8; ++kc)
            af[kc] = *(const bf16x8*)(dfrag + (((size_t)(c * MAXT + t) * 8 + kc) * 64 + lane) * 8);
        int tm = tilemod[c * MAXT + t];   // wave-uniform
#pragma unroll
        for (int bi = 0; bi < 2; ++bi) {
            f32x16 acc = {0.f,0.f,0.f,0.f,0.f,0.f,0.f,0.f,0.f,0.f,0.f,0.f,0.f,0.f,0.f,0.f};
#pragma unroll
            for (int kc = 0; kc < 8; ++kc)
                acc = __builtin_amdgcn_mfma_f32_32x32x16_bf16(af[kc], bfrag[bi][kc], acc, 0, 0, 0);
            float v = acc[0];
#pragma unroll
            for (int r = 1; r < 16; ++r) v = fmaxf(v, acc[r]);
            v = fmaxf(v, __shfl_xor(v, 32, 64));
            switch (tm) {
            case 1:  vmax[bi][0] = fmaxf(vmax[bi][0], v); break;
            case 2:  vmax[bi][1] = fmaxf(vmax[bi][1], v); break;
            case 3:  vmax[bi][2] = fmaxf(vmax[bi][2], v); break;
            default: vmax[bi][3] = fmaxf(vmax[bi][3], v); break;
            }
        }
    }

    __shared__ float lv[4][2][4][32];   // 4 KB
    if (lane < 32) {
#pragma unroll
        for (int bi = 0; bi < 2; ++bi)
#pragma unroll
            for (int m = 0; m < 4; ++m) lv[wv][bi][m][lane] = vmax[bi][m];
    }
    __syncthreads();
    __shared__ float l2s[2][4][32];     // 1 KB
    {
        int bi = tid >> 7, m = (tid >> 5) & 3, q = tid & 31;
        float v = fmaxf(fmaxf(lv[0][bi][m][q], lv[1][bi][m][q]),
                        fmaxf(lv[2][bi][m][q], lv[3][bi][m][q]));
        l2s[bi][m][q] = v;
    }
    __syncthreads();
    if (tid < 64) {
        int bi = tid >> 5, q = tid & 31;
        float m1 = l2s[bi][0][q], m2 = l2s[bi][1][q];
        float m3 = l2s[bi][2][q], m4 = l2s[bi][3][q];
        int b = b0 + bi;
        float agg = fmaxf(fmaxf(m1, m2), fmaxf(m3, m4));
        float s0 = (qmask[b * NQ + q] != 0) ? agg : 0.f;
        float s1 = m1, s2 = m2, s3 = m3, s4 = m4;
#pragma unroll
        for (int off = 16; off >= 1; off >>= 1) {
            s0 += __shfl_xor(s0, off, 64);
            s1 += __shfl_xor(s1, off, 64);
            s2 += __shfl_xor(s2, off, 64);
            s3 += __shfl_xor(s3, off, 64);
            s4 += __shfl_xor(s4, off, 64);
        }
        if (q == 0) {
            float* o = simout + ((size_t)b * NB + c) * 5;   // UNNORMALIZED sums
            o[0] = s0; o[1] = s1; o[2] = s2; o[3] = s3; o[4] = s4;
        }
    }
}

// ---------------------------------------------------------------------------
// Kernel 3: loss, 64 blocks (one per row). Row's 320 floats load coalesced;
// two-pass logsumexp via shfl+LDS block reduce. Row losses combined with a
// device-coherent fp32 atomicAdd (no __threadfence — R3 lesson); ordering to
// the counter enforced by data-dependence on the atomic's return value.
// ---------------------------------------------------------------------------
__global__ __launch_bounds__(256) void
loss_kernel(const float* __restrict__ simout, const int* __restrict__ qtypes,
            const int* __restrict__ qmask, int* __restrict__ red,
            float* __restrict__ out) {
    int r = blockIdx.x;
    int tid = threadIdx.x;
    int lane = tid & 63, wv = tid >> 6;

    __shared__ float sv[320];
    for (int i = tid; i < 320; i += 256) sv[i] = simout[(size_t)r * 320 + i];

    // qnorm via ballot on wave 0
    __shared__ int scnt;
    if (wv == 0) {
        int on = (lane < NQ) ? (qmask[r * NQ + lane] != 0) : 0;
        unsigned long long bal = __ballot(on);
        if (lane == 0) scnt = __popcll(bal);
    }
    __syncthreads();
    int cq = scnt;
    float scale = 1.0f / (TAU_F * (float)(cq > 0 ? cq : 1));
    int skip = r * 5;                      // the agg-sim diagonal slot

    __shared__ float wred[4];
    // pass 1: max
    float mx = -1e30f;
    for (int i = tid; i < 320; i += 256)
        if (i != skip) mx = fmaxf(mx, sv[i] * scale);
#pragma unroll
    for (int off = 32; off >= 1; off >>= 1) mx = fmaxf(mx, __shfl_xor(mx, off, 64));
    if (lane == 0) wred[wv] = mx;
    __syncthreads();
    mx = fmaxf(fmaxf(wred[0], wred[1]), fmaxf(wred[2], wred[3]));

    // pass 2: sum of exp
    float sum = 0.f;
    for (int i = tid; i < 320; i += 256)
        if (i != skip) sum += expf(sv[i] * scale - mx);
#pragma unroll
    for (int off = 32; off >= 1; off >>= 1) sum += __shfl_xor(sum, off, 64);
    __syncthreads();
    if (lane == 0) wred[wv] = sum;
    __syncthreads();

    if (tid == 0) {
        float tot = wred[0] + wred[1] + wred[2] + wred[3];
        float pos = sv[r * 5 + qtypes[r]] * scale;
        float lr = (logf(tot) + mx - pos) * (1.0f / NB);
        float* acc = (float*)red + 16;
        float ret = atomicAdd(acc, lr);                  // device-coherent
        int bump = 1 + (ret > 1e37f ? 1 : 0);            // data-dep: wait ret
        int old = atomicAdd(red, bump);
        if (old == NB - 1) {
            float v = atomicAdd(acc, 0.f);               // coherent read-back
            out[0] = v;
        }
    }
}

// ---------------------------------------------------------------------------
extern "C" void kernel_launch(void* const* d_in, const int* in_sizes, int n_in,
                              void* d_out, int out_size, void* d_ws, size_t ws_size,
                              hipStream_t stream) {
    const float* qemb   = (const float*)d_in[0];
    const float* demb   = (const float*)d_in[1];
    const int*   mod    = (const int*)d_in[2];
    const int*   qtypes = (const int*)d_in[3];
    const int*   qmask  = (const int*)d_in[4];

    char* ws = (char*)d_ws;
    int*    tilemod = (int*)(ws + OFF_TILEMOD);
    int*    tcount  = (int*)(ws + OFF_TCOUNT);
    __bf16* dfrag   = (__bf16*)(ws + OFF_DFRAG);
    __bf16* qfrag   = (__bf16*)(ws + OFF_QFRAG);
    float*  simout  = (float*)(ws + OFF_SIMOUT);
    int*    red     = (int*)(ws + OFF_RED);

    prep_frag_kernel<<<2 * NB, 256, 0, stream>>>(qemb, demb, mod, qfrag, dfrag,
                                                 tilemod, tcount, red);
    main_kernel<<<2048, 256, 0, stream>>>(dfrag, qfrag, tilemod, tcount, qmask, simout);
    loss_kernel<<<NB, 256, 0, stream>>>(simout, qtypes, qmask, red, (float*)d_out);
}